// Round 11
// baseline (74.904 us; speedup 1.0000x reference)
//
#include <hip/hip_runtime.h>

#define DIM   4096
#define RANK  16
#define BM    16     // rows per tile = MFMA M
#define NT    1024   // 16 waves: 0-7 A-crew (dots), 8-15 B-crew (apply)
#define NAW   8      // A-crew waves
#define TPB   2      // tiles per block
#define NST   8      // sub-tiles per wave per tile (k-slice 512 = 8 x 64 floats)

typedef __fp16 f16;
typedef __fp16 half4 __attribute__((ext_vector_type(4)));
typedef __fp16 half8 __attribute__((ext_vector_type(8)));
typedef float  floatx4 __attribute__((ext_vector_type(4)));

// counted vmcnt wait + scheduling fence (rule #18)
#define VM_WAIT(N) { asm volatile("s_waitcnt vmcnt(" #N ")" ::: "memory"); \
                     __builtin_amdgcn_sched_barrier(0); }
#define SCHED_FENCE() __builtin_amdgcn_sched_barrier(0)

// async global->LDS DMA, 16 B per lane; LDS dest = uniform base + lane*16
__device__ __forceinline__ void gld16(const void* g, void* l) {
    __builtin_amdgcn_global_load_lds((__attribute__((address_space(1))) void*)g,
                                     (__attribute__((address_space(3))) void*)l,
                                     16, 0, 0);
}

// ---- prep: weights in exact MFMA fragment order (unchanged, proven) ----
__global__ __launch_bounds__(256) void prep_weights(const float* __restrict__ U,
    const float* __restrict__ nw, const float* __restrict__ V,
    f16* __restrict__ Ub, f16* __restrict__ Vb)
{
    const int i   = blockIdx.x * 256 + threadIdx.x;   // 0..16383
    const int l   = i & 63;
    const int n   = l & 15;
    const int blk = l >> 4;
    if (i < 8192) {                     // Ub: 128 kb-steps x 64 lanes
        const int kb = i >> 6;
        half8 u;
        #pragma unroll
        for (int e = 0; e < 8; ++e) {
            const int k = kb * 32 + blk * 8 + e;
            u[e] = (f16)(nw[k] * U[(size_t)k * RANK + n]);
        }
        *(half8*)(Ub + (size_t)i * 8) = u;
    }
    {                                   // Vb: 256 col-blocks x 64 lanes
        const int cb = i >> 6;
        half4 v;
        #pragma unroll
        for (int e = 0; e < 4; ++e) {
            const int k = blk * 4 + e;
            v[e] = (f16)V[(size_t)k * DIM + cb * 16 + n];
        }
        *(half4*)(Vb + (size_t)i * 4) = v;
    }
}

// ---- fused producer/consumer kernel ----
// A-crew (waves 0-7): R10's DMA-ring MFMA dots over 2 tiles; per-tile publish
// via LDS slots + atomic counter; LAST wave combines (rstd + S*keep) and sets
// the tile flag. B-crew (waves 8-15): spin (s_sleep) on flag, then R7 apply.
// B(tile i) overlaps A(tile i+1) -> chip-wide mixed read+write streams.
// NO __syncthreads after init -> crews can never deadlock on a barrier.
__global__ __launch_bounds__(NT, 4) void arl_fused(
    const float* __restrict__ x,  const f16* __restrict__ Ub,
    const f16* __restrict__ Vb,   const float* __restrict__ S,
    const float* __restrict__ gamma, float* __restrict__ out)
{
    const int t   = threadIdx.x;
    const int w   = t >> 6;
    const int l   = t & 63;
    const int n   = l & 15;     // A-frag row / B,D-frag col
    const int blk = l >> 4;     // k-block / D row-group
    const size_t rowB = (size_t)blockIdx.x * (BM * TPB);   // block's 32 rows

    __shared__ __align__(16) float ring[NAW][2][BM * 64];  // 64 KB DMA ring
    __shared__ float s_hacc[TPB][NAW][16][17];             // 17.4 KB (+1 pad)
    __shared__ float s_ssq[TPB][NAW][16];                  // 1 KB
    __shared__ __align__(8) f16 s_hh[TPB][16][16];         // 1 KB
    __shared__ int s_cnt[TPB];
    __shared__ int s_flag[TPB];

    if (t == 0) { s_cnt[0] = 0; s_cnt[1] = 0; s_flag[0] = 0; s_flag[1] = 0; }
    __syncthreads();                    // ONLY barrier; all threads reach it

    if (w < NAW) {
        // ======================= A-crew: dots producer =======================
        floatx4 acc = {0.f, 0.f, 0.f, 0.f};
        float ssq = 0.f;

        // prologue: global subtile 0 (tile 0, st 0) -> buf 0
        #pragma unroll
        for (int j = 0; j < 4; ++j) {
            const int rl  = 4 * j + (l >> 4);
            const int gsw = (l & 15) ^ (rl & 7);
            gld16(x + (rowB + rl) * DIM + (size_t)w * 512 + gsw * 4,
                  &ring[w][0][j * 256]);
        }

        #pragma unroll 1
        for (int g = 0; g < TPB * NST; ++g) {
            const int st = g & (NST - 1);
            // Ub for this sub-tile's 2 k-steps (VGPR loads BEFORE next DMAs:
            // FIFO puts the compiler's ub-wait at vmcnt(4), never 0)
            const int kb0 = w * 16 + st * 2;
            const half8 ub0 = *(const half8*)(Ub + ((size_t)kb0 * 64 + l) * 8);
            const half8 ub1 = *(const half8*)(Ub + ((size_t)(kb0 + 1) * 64 + l) * 8);
            SCHED_FENCE();
            if (g + 1 < TPB * NST) {    // issue next subtile -> stays in flight
                const int tn = (g + 1) >> 3, sn = (g + 1) & (NST - 1);
                #pragma unroll
                for (int j = 0; j < 4; ++j) {
                    const int rl  = 4 * j + (l >> 4);
                    const int gsw = (l & 15) ^ (rl & 7);
                    gld16(x + (rowB + tn * BM + rl) * DIM + (size_t)w * 512
                            + (size_t)sn * 64 + gsw * 4,
                          &ring[w][(g + 1) & 1][j * 256]);
                }
                VM_WAIT(6)              // subtile g's 4 DMAs retired
            } else {
                VM_WAIT(2)              // tail: only ub may remain
            }

            const float* buf = ring[w][g & 1];
            #pragma unroll
            for (int s = 0; s < 2; ++s) {
                const int g0 = (s * 8 + blk * 2)     ^ (n & 7);
                const int g1 = (s * 8 + blk * 2 + 1) ^ (n & 7);
                const float4 xa0 = *(const float4*)&buf[n * 64 + g0 * 4];
                const float4 xa1 = *(const float4*)&buf[n * 64 + g1 * 4];
                ssq = fmaf(xa0.x, xa0.x, ssq); ssq = fmaf(xa0.y, xa0.y, ssq);
                ssq = fmaf(xa0.z, xa0.z, ssq); ssq = fmaf(xa0.w, xa0.w, ssq);
                ssq = fmaf(xa1.x, xa1.x, ssq); ssq = fmaf(xa1.y, xa1.y, ssq);
                ssq = fmaf(xa1.z, xa1.z, ssq); ssq = fmaf(xa1.w, xa1.w, ssq);
                half8 a;
                a[0] = (f16)xa0.x; a[1] = (f16)xa0.y; a[2] = (f16)xa0.z; a[3] = (f16)xa0.w;
                a[4] = (f16)xa1.x; a[5] = (f16)xa1.y; a[6] = (f16)xa1.z; a[7] = (f16)xa1.w;
                acc = __builtin_amdgcn_mfma_f32_16x16x32_f16(a, s ? ub1 : ub0, acc, 0, 0, 0);
            }

            if (st == NST - 1) {        // tile (g>>3) finished for this wave
                const int ti = g >> 3;
                float sq = ssq;
                sq += __shfl_xor(sq, 16, 64);
                sq += __shfl_xor(sq, 32, 64);
                if (l < 16) s_ssq[ti][w][l] = sq;
                #pragma unroll
                for (int j = 0; j < 4; ++j) s_hacc[ti][w][blk * 4 + j][n] = acc[j];
                __threadfence_block();                 // drain LDS writes
                int r = 0;
                if (l == 0) r = atomicAdd(&s_cnt[ti], 1);
                r = __shfl(r, 0, 64);
                if (r == NAW - 1) {
                    // -------- combiner: this wave's 64 lanes fold 256 h's --------
                    float tot = 0.f;
                    #pragma unroll
                    for (int i = 0; i < RANK; ++i) tot += fabsf(S[i]);
                    const float denom = fmaxf(tot, 1e-8f);
                    #pragma unroll
                    for (int j = 0; j < 4; ++j) {
                        const int p = l * 4 + j;       // 0..255
                        const int m = p >> 4, q = p & 15;
                        float hsum = 0.f, tssq = 0.f;
                        #pragma unroll
                        for (int ww = 0; ww < NAW; ++ww) {
                            hsum += s_hacc[ti][ww][m][q];
                            tssq += s_ssq[ti][ww][m];
                        }
                        const float rstd = rsqrtf(tssq * (1.0f / DIM) + 1e-6f);
                        float cum = 0.f, se = 0.f;
                        #pragma unroll
                        for (int i = 0; i < RANK; ++i) {
                            if (i == q) se = ((cum / denom) < 0.95f) ? S[i] : 0.f;
                            cum += fabsf(S[i]);
                        }
                        s_hh[ti][m][q] = (f16)(hsum * se * rstd);
                    }
                    __threadfence_block();             // h visible before flag
                    if (l == 0) atomicExch(&s_flag[ti], 1);
                }
                acc[0] = 0.f; acc[1] = 0.f; acc[2] = 0.f; acc[3] = 0.f;
                ssq = 0.f;
            }
        }
        // A-crew exits; B-crew keeps the block alive
    } else {
        // ======================= B-crew: apply consumer =======================
        const int wb = w - NAW;         // 0..7
        const half4* Vb4 = (const half4*)Vb;
        const floatx4 zero = {0.f, 0.f, 0.f, 0.f};

        #pragma unroll 1
        for (int ti = 0; ti < TPB; ++ti) {
            // spin until A-crew publishes h for tile ti (s_sleep = polite poll)
            int ready = 0;
            while (!ready) {
                if (l == 0) ready = atomicAdd(&s_flag[ti], 0);
                ready = __shfl(ready, 0, 64);
                if (!ready) __builtin_amdgcn_s_sleep(8);
            }

            const half4 ah = *(const half4*)&s_hh[ti][n][blk * 4];
            const size_t row0 = rowB + (size_t)ti * BM;
            const float* xrow = x   + (row0 + n) * DIM;   // L3-hot (A just read)
            float*       orow = out + (row0 + n) * DIM;

            #pragma unroll 4
            for (int i = 0; i < 32; ++i) {
                const int cb = wb * 32 + i;
                const int c0 = cb * 16 + blk * 4;
                const half4 bv = Vb4[(size_t)cb * 64 + l];     // L2-hot
                floatx4 d = __builtin_amdgcn_mfma_f32_16x16x16f16(bv, ah, zero, 0, 0, 0);
                const float4 g  = *(const float4*)(gamma + c0);
                const float4 xv = *(const float4*)(xrow + c0);
                floatx4 o;
                o[0] = fmaf(g.x, d[0], xv.x);
                o[1] = fmaf(g.y, d[1], xv.y);
                o[2] = fmaf(g.z, d[2], xv.z);
                o[3] = fmaf(g.w, d[3], xv.w);
                __builtin_nontemporal_store(o, (floatx4*)(orow + c0));
            }
        }
    }
}

extern "C" void kernel_launch(void* const* d_in, const int* in_sizes, int n_in,
                              void* d_out, int out_size, void* d_ws, size_t ws_size,
                              hipStream_t stream) {
    (void)in_sizes; (void)n_in; (void)ws_size;
    const float* x  = (const float*)d_in[0];
    const float* U  = (const float*)d_in[1];
    const float* S  = (const float*)d_in[2];
    const float* V  = (const float*)d_in[3];
    const float* nw = (const float*)d_in[4];
    const float* g  = (const float*)d_in[5];
    float* out = (float*)d_out;
    f16* Ub = (f16*)d_ws;                          // 128 KB fragment-order U'
    f16* Vb = (f16*)((char*)d_ws + 128 * 1024);    // 128 KB fragment-order V

    hipLaunchKernelGGL(prep_weights, dim3(64), dim3(256), 0, stream,
                       U, nw, V, Ub, Vb);

    const int rows = out_size / DIM;               // 8192
    const int grid = rows / (BM * TPB);            // 256 = 1 block/CU
    hipLaunchKernelGGL(arl_fused, dim3(grid), dim3(NT), 0, stream,
                       x, Ub, Vb, S, g, out);
}